// Round 4
// baseline (685.985 us; speedup 1.0000x reference)
//
#include <hip/hip_runtime.h>
#include <hip/hip_bf16.h>
#include <math.h>

#define N_PROTS 2048
#define N_MOLS  16384
#define DIM     768
#define SHIFT   16.0f
#define MARGIN  0.5f

typedef __attribute__((ext_vector_type(8))) short short8;
typedef __attribute__((ext_vector_type(4))) float f32x4;
typedef __attribute__((ext_vector_type(4))) unsigned short us4;
typedef __attribute__((ext_vector_type(8))) unsigned short us8;

__device__ __forceinline__ unsigned short bf16rnd(float x) {
    unsigned int u = __float_as_uint(x);
    u += 0x7fffu + ((u >> 16) & 1u);   // round-to-nearest-even
    return (unsigned short)(u >> 16);
}

__device__ __forceinline__ void gload16(const void* g, void* l) {
    __builtin_amdgcn_global_load_lds(
        (const __attribute__((address_space(1))) unsigned int*)g,
        (__attribute__((address_space(3))) unsigned int*)l, 16, 0, 0);
}

// ws layout:
//  floats [0, 34824): 0..2048 row_sumexp | 2048..18432 col_sumexp |
//                     18432..34816 pos_sim | 34816..34824 scalars
//  then 16B-aligned: protBf (2048*768 bf16), molBf (16384*768 bf16)
#define ACC_FLOATS 34824
#define PROT_BF_OFF_B 139296ull                      // 34824*4, 16B aligned
#define PROT_BF_BYTES (2048ull*768*2)
#define MOL_BF_OFF_B  (PROT_BF_OFF_B + PROT_BF_BYTES)
#define MOL_BF_BYTES  (16384ull*768*2)
#define WS_NEED       (MOL_BF_OFF_B + MOL_BF_BYTES)  // ~28.5 MB

// ---------------- one-shot fp32 -> bf16 conversion ----------------
__global__ __launch_bounds__(256)
void convert_bf16(const float* __restrict__ prot, const float* __restrict__ mol,
                  unsigned short* __restrict__ protBf, unsigned short* __restrict__ molBf)
{
    const size_t PROT_G = (size_t)N_PROTS * DIM / 8;   // groups of 8 elems
    size_t t = (size_t)blockIdx.x * 256 + threadIdx.x;
    const float* src;
    unsigned short* dst;
    if (t < PROT_G) { src = prot + t * 8; dst = protBf + t * 8; }
    else            { size_t u = t - PROT_G; src = mol + u * 8; dst = molBf + u * 8; }
    float4 v0 = ((const float4*)src)[0];
    float4 v1 = ((const float4*)src)[1];
    us8 o;
    o[0] = bf16rnd(v0.x); o[1] = bf16rnd(v0.y); o[2] = bf16rnd(v0.z); o[3] = bf16rnd(v0.w);
    o[4] = bf16rnd(v1.x); o[5] = bf16rnd(v1.y); o[6] = bf16rnd(v1.z); o[7] = bf16rnd(v1.w);
    *(us8*)dst = o;
}

// ------- bf16 GEMM: 256x256 tile, 8 waves, dbuf global_load_lds, XCD swizzle -------
__global__ __launch_bounds__(512, 4)
void sim_pass_bf16(const unsigned short* __restrict__ protBf,
                   const unsigned short* __restrict__ molBf,
                   const float* __restrict__ scale_p,
                   float* __restrict__ row_se, float* __restrict__ col_se,
                   float* __restrict__ pos_sim, float* __restrict__ scalars)
{
    __shared__ unsigned short As[2][256][32];
    __shared__ unsigned short Bs[2][256][32];
    __shared__ float redBuf[8];

    const int tid = threadIdx.x;
    // XCD-aware remap: each XCD (l&7) owns an 8-wide bx band -> its B working
    // set is 8*256 mol rows = 3 MB, fits the 4 MB XCD L2.
    const int l    = blockIdx.y * 64 + blockIdx.x;     // 0..511
    const int xcd  = l & 7;
    const int slot = l >> 3;                           // 0..63
    const int bx   = xcd * 8 + (slot & 7);             // 0..63
    const int by   = slot >> 3;                        // 0..7
    const int rowBase = by * 256;
    const int colBase = bx * 256;

    const int wave = tid >> 6;         // 0..7
    const int lane = tid & 63;
    const int wr = (wave >> 1) * 64;   // 0,64,128,192
    const int wc = (wave & 1) * 128;   // 0,128
    const int l15 = lane & 15;
    const int q   = lane >> 4;

    f32x4 acc[4][8];
#pragma unroll
    for (int i = 0; i < 4; ++i)
#pragma unroll
        for (int j = 0; j < 8; ++j) acc[i][j] = (f32x4){0.f, 0.f, 0.f, 0.f};

    // staging: lane covers 16 B; rows r0 and r0+128 (2 rounds per matrix).
    // XOR-swizzle the SOURCE chunk (LDS dest must stay lane-contiguous):
    // LDS chunk c holds global chunk c ^ ((row>>1)&3); (r0+128) has the same
    // swizzle, so one source offset serves both rounds.
    const int r0   = tid >> 2;                               // 0..127
    const int csrc = ((tid & 3) ^ ((r0 >> 1) & 3)) << 3;     // halfword offset
    const unsigned short* aP0 = protBf + (size_t)(rowBase + r0) * DIM + csrc;
    const unsigned short* aP1 = aP0 + (size_t)128 * DIM;
    const unsigned short* bP0 = molBf + (size_t)(colBase + r0) * DIM + csrc;
    const unsigned short* bP1 = bP0 + (size_t)128 * DIM;
    // wave-uniform LDS bases (hardware writes base + lane*16B):
    // wave w round 0 covers rows [16w,16w+16) -> halfword offset 512w
    unsigned short* ldsA0 = &As[0][0][0] + (wave << 9);
    unsigned short* ldsB0 = &Bs[0][0][0] + (wave << 9);

    // prologue: stage tile 0 into buffer 0
    gload16(aP0, ldsA0);
    gload16(aP1, ldsA0 + 4096);
    gload16(bP0, ldsB0);
    gload16(bP1, ldsB0 + 4096);

#pragma unroll 1
    for (int s = 0; s < DIM / 32; ++s) {
        const int cur = s & 1;
        __syncthreads();   // drains tile-s loads (issued one full iter ago)

        if (s + 1 < DIM / 32) {
            const int ko = (s + 1) * 32;
            const int nb = (cur ^ 1) * 8192;
            gload16(aP0 + ko, ldsA0 + nb);
            gload16(aP1 + ko, ldsA0 + nb + 4096);
            gload16(bP0 + ko, ldsB0 + nb);
            gload16(bP1 + ko, ldsB0 + nb + 4096);
        }

        short8 aF[4], bF[8];
#pragma unroll
        for (int mi = 0; mi < 4; ++mi) {
            const int R = wr + mi * 16 + l15;
            aF[mi] = *(const short8*)&As[cur][R][(q ^ ((R >> 1) & 3)) << 3];
        }
#pragma unroll
        for (int ni = 0; ni < 8; ++ni) {
            const int R = wc + ni * 16 + l15;
            bF[ni] = *(const short8*)&Bs[cur][R][(q ^ ((R >> 1) & 3)) << 3];
        }
#pragma unroll
        for (int mi = 0; mi < 4; ++mi)
#pragma unroll
            for (int ni = 0; ni < 8; ++ni)
                acc[mi][ni] = __builtin_amdgcn_mfma_f32_16x16x32_bf16(aF[mi], bF[ni], acc[mi][ni], 0, 0, 0);
    }

    // ---------------- epilogue ----------------
    const float scale = scale_p[0];
    float rsum[4][4];
    float csum[8];
    float rl = 0.f;
#pragma unroll
    for (int mi = 0; mi < 4; ++mi)
#pragma unroll
        for (int r = 0; r < 4; ++r) rsum[mi][r] = 0.f;
#pragma unroll
    for (int ni = 0; ni < 8; ++ni) csum[ni] = 0.f;

#pragma unroll
    for (int mi = 0; mi < 4; ++mi) {
#pragma unroll
        for (int ni = 0; ni < 8; ++ni) {
#pragma unroll
            for (int r = 0; r < 4; ++r) {
                float sim = acc[mi][ni][r] * scale;
                float e = __expf(sim - SHIFT);
                rsum[mi][r] += e;
                csum[ni] += e;
                rl += fmaxf(sim, 0.f);
                int rg = rowBase + wr + mi * 16 + q * 4 + r;
                int cg = colBase + wc + ni * 16 + l15;
                if ((cg >> 3) == rg) pos_sim[cg] = sim;   // unique writer
            }
        }
    }

#pragma unroll
    for (int mi = 0; mi < 4; ++mi) {
#pragma unroll
        for (int r = 0; r < 4; ++r) {
            float v = rsum[mi][r];
            v += __shfl_xor(v, 1); v += __shfl_xor(v, 2);
            v += __shfl_xor(v, 4); v += __shfl_xor(v, 8);
            if (l15 == 0)
                atomicAdd(&row_se[rowBase + wr + mi * 16 + q * 4 + r], v);
        }
    }
#pragma unroll
    for (int ni = 0; ni < 8; ++ni) {
        float v = csum[ni];
        v += __shfl_xor(v, 16); v += __shfl_xor(v, 32);
        if (q == 0)
            atomicAdd(&col_se[colBase + wc + ni * 16 + l15], v);
    }
#pragma unroll
    for (int m = 1; m < 64; m <<= 1) rl += __shfl_xor(rl, m);
    if (lane == 0) redBuf[wave] = rl;
    __syncthreads();
    if (tid == 0) {
        float t = 0.f;
        for (int w = 0; w < 8; ++w) t += redBuf[w];
        atomicAdd(&scalars[0], t);
    }
}

// ---------------- fallback: fp32-staging GEMM (R1 kernel) ----------------
__global__ __launch_bounds__(256, 2)
void sim_pass(const float* __restrict__ prot, const float* __restrict__ mol,
              const float* __restrict__ scale_p,
              float* __restrict__ row_se, float* __restrict__ col_se,
              float* __restrict__ pos_sim, float* __restrict__ scalars)
{
    __shared__ unsigned short As[128][32];
    __shared__ unsigned short Bs[128][32];
    __shared__ float redBuf[4];

    const int tid = threadIdx.x;
    const int rowBase = blockIdx.y * 128;
    const int colBase = blockIdx.x * 128;
    const int wave = tid >> 6;
    const int lane = tid & 63;
    const int wr = (wave >> 1) * 64;
    const int wc = (wave & 1) * 64;
    const int l15 = lane & 15;
    const int q   = lane >> 4;

    f32x4 acc[4][4];
#pragma unroll
    for (int i = 0; i < 4; ++i)
#pragma unroll
        for (int j = 0; j < 4; ++j) acc[i][j] = (f32x4){0.f, 0.f, 0.f, 0.f};

    const float* aBase = prot + (size_t)rowBase * DIM;
    const float* bBase = mol  + (size_t)colBase * DIM;
    float4 aReg[4], bReg[4];
#pragma unroll
    for (int i = 0; i < 4; ++i) {
        int f = tid + 256 * i;
        int row = f >> 3, c4 = f & 7;
        aReg[i] = *(const float4*)(aBase + (size_t)row * DIM + (c4 << 2));
        bReg[i] = *(const float4*)(bBase + (size_t)row * DIM + (c4 << 2));
    }
#pragma unroll 1
    for (int s = 0; s < DIM / 32; ++s) {
#pragma unroll
        for (int i = 0; i < 4; ++i) {
            int f = tid + 256 * i;
            int row = f >> 3, c4 = f & 7;
            us4 av, bv;
            av.x = bf16rnd(aReg[i].x); av.y = bf16rnd(aReg[i].y);
            av.z = bf16rnd(aReg[i].z); av.w = bf16rnd(aReg[i].w);
            bv.x = bf16rnd(bReg[i].x); bv.y = bf16rnd(bReg[i].y);
            bv.z = bf16rnd(bReg[i].z); bv.w = bf16rnd(bReg[i].w);
            *(us4*)&As[row][c4 << 2] = av;
            *(us4*)&Bs[row][c4 << 2] = bv;
        }
        __syncthreads();
        if (s + 1 < DIM / 32) {
            int k0 = (s + 1) * 32;
#pragma unroll
            for (int i = 0; i < 4; ++i) {
                int f = tid + 256 * i;
                int row = f >> 3, c4 = f & 7;
                aReg[i] = *(const float4*)(aBase + (size_t)row * DIM + k0 + (c4 << 2));
                bReg[i] = *(const float4*)(bBase + (size_t)row * DIM + k0 + (c4 << 2));
            }
        }
        short8 aF[4], bF[4];
#pragma unroll
        for (int mi = 0; mi < 4; ++mi) aF[mi] = *(const short8*)&As[wr + mi * 16 + l15][q * 8];
#pragma unroll
        for (int ni = 0; ni < 4; ++ni) bF[ni] = *(const short8*)&Bs[wc + ni * 16 + l15][q * 8];
#pragma unroll
        for (int mi = 0; mi < 4; ++mi)
#pragma unroll
            for (int ni = 0; ni < 4; ++ni)
                acc[mi][ni] = __builtin_amdgcn_mfma_f32_16x16x32_bf16(aF[mi], bF[ni], acc[mi][ni], 0, 0, 0);
        __syncthreads();
    }

    const float scale = scale_p[0];
    float rsum[4][4];
    float csum[4] = {0.f, 0.f, 0.f, 0.f};
    float rl = 0.f;
#pragma unroll
    for (int mi = 0; mi < 4; ++mi)
#pragma unroll
        for (int r = 0; r < 4; ++r) rsum[mi][r] = 0.f;
#pragma unroll
    for (int mi = 0; mi < 4; ++mi) {
#pragma unroll
        for (int ni = 0; ni < 4; ++ni) {
#pragma unroll
            for (int r = 0; r < 4; ++r) {
                float sim = acc[mi][ni][r] * scale;
                float e = __expf(sim - SHIFT);
                rsum[mi][r] += e;
                csum[ni] += e;
                rl += fmaxf(sim, 0.f);
                int rg = rowBase + wr + mi * 16 + q * 4 + r;
                int cg = colBase + wc + ni * 16 + l15;
                if ((cg >> 3) == rg) pos_sim[cg] = sim;
            }
        }
    }
#pragma unroll
    for (int mi = 0; mi < 4; ++mi) {
#pragma unroll
        for (int r = 0; r < 4; ++r) {
            float v = rsum[mi][r];
            v += __shfl_xor(v, 1); v += __shfl_xor(v, 2);
            v += __shfl_xor(v, 4); v += __shfl_xor(v, 8);
            if (l15 == 0)
                atomicAdd(&row_se[rowBase + wr + mi * 16 + q * 4 + r], v);
        }
    }
#pragma unroll
    for (int ni = 0; ni < 4; ++ni) {
        float v = csum[ni];
        v += __shfl_xor(v, 16); v += __shfl_xor(v, 32);
        if (q == 0)
            atomicAdd(&col_se[colBase + wc + ni * 16 + l15], v);
    }
#pragma unroll
    for (int m = 1; m < 64; m <<= 1) rl += __shfl_xor(rl, m);
    if (lane == 0) redBuf[wave] = rl;
    __syncthreads();
    if (tid == 0)
        atomicAdd(&scalars[0], redBuf[0] + redBuf[1] + redBuf[2] + redBuf[3]);
}

// ---------------- finalize ----------------
__global__ __launch_bounds__(256)
void finalize1(const float* __restrict__ row_se, const float* __restrict__ col_se,
               const float* __restrict__ pos_sim, const float* __restrict__ pic50,
               float* __restrict__ scalars)
{
    int j = blockIdx.x * 256 + threadIdx.x;   // mol index
    float m2p = SHIFT + __logf(col_se[j]) - pos_sim[j];

    float p2m = 0.f, rank = 0.f, prelu = 0.f;
    if ((j & 7) == 0) {
        int i = j >> 3;
        float s[8], pc[8], pr[8];
#pragma unroll
        for (int p = 0; p < 8; ++p) {
            s[p]  = pos_sim[j + p];
            pr[p] = pic50[(size_t)i * N_MOLS + j + p];
            float x = (pr[p] - 2.0f) * 0.125f;
            pc[p] = fminf(fmaxf(x, 0.f), 1.f);
            prelu += fmaxf(s[p], 0.f);
        }
        float wsum = 1e-8f;
#pragma unroll
        for (int p = 0; p < 8; ++p) wsum += pc[p];
        float lse = SHIFT + __logf(row_se[i]);
        float accp = 0.f;
#pragma unroll
        for (int p = 0; p < 8; ++p) accp += pc[p] * (lse - s[p]);
        p2m = accp / wsum;
#pragma unroll
        for (int a = 0; a < 8; ++a)
#pragma unroll
            for (int b = a + 1; b < 8; ++b) {
                float dp = pr[a] - pr[b];
                float ds = s[a] - s[b];
                float v = (dp > 0.f) ? fmaxf(MARGIN - ds, 0.f)
                        : ((dp < 0.f) ? fmaxf(MARGIN + ds, 0.f) : 0.f);
                rank += v;
            }
    }

#pragma unroll
    for (int m = 1; m < 64; m <<= 1) {
        m2p   += __shfl_xor(m2p, m);
        p2m   += __shfl_xor(p2m, m);
        rank  += __shfl_xor(rank, m);
        prelu += __shfl_xor(prelu, m);
    }
    __shared__ float rbuf[4][4];
    int wave = threadIdx.x >> 6, lane = threadIdx.x & 63;
    if (lane == 0) { rbuf[wave][0] = m2p; rbuf[wave][1] = p2m; rbuf[wave][2] = rank; rbuf[wave][3] = prelu; }
    __syncthreads();
    if (threadIdx.x == 0) {
        float a = 0, b = 0, c = 0, d = 0;
        for (int w = 0; w < 4; ++w) { a += rbuf[w][0]; b += rbuf[w][1]; c += rbuf[w][2]; d += rbuf[w][3]; }
        atomicAdd(&scalars[2], a);
        atomicAdd(&scalars[1], b);
        atomicAdd(&scalars[3], c);
        atomicAdd(&scalars[4], d);
    }
}

__global__ void finalize2(const float* __restrict__ scalars, float* __restrict__ out)
{
    float relu_neg = scalars[0] - scalars[4];
    float p2m  = scalars[1] / (float)N_PROTS;
    float m2p  = scalars[2] / (float)N_MOLS;
    float rank = scalars[3] / ((float)N_PROTS * 28.0f);
    float neg  = relu_neg / ((float)N_PROTS * (float)N_MOLS);
    out[0] = p2m + m2p + 0.5f * rank + 0.1f * neg;
    out[1] = p2m;
    out[2] = m2p;
    out[3] = rank;
    out[4] = neg;
}

extern "C" void kernel_launch(void* const* d_in, const int* in_sizes, int n_in,
                              void* d_out, int out_size, void* d_ws, size_t ws_size,
                              hipStream_t stream) {
    const float* prot   = (const float*)d_in[0];
    const float* mol    = (const float*)d_in[1];
    const float* pic50  = (const float*)d_in[3];
    const float* lscale = (const float*)d_in[4];

    float* ws      = (float*)d_ws;
    float* row_se  = ws;
    float* col_se  = ws + 2048;
    float* pos_sim = ws + 2048 + 16384;
    float* scalars = ws + 2048 + 16384 + 16384;

    hipMemsetAsync(d_ws, 0, (size_t)ACC_FLOATS * sizeof(float), stream);

    if (ws_size >= WS_NEED) {
        unsigned short* protBf = (unsigned short*)((char*)d_ws + PROT_BF_OFF_B);
        unsigned short* molBf  = (unsigned short*)((char*)d_ws + MOL_BF_OFF_B);
        size_t groups = ((size_t)N_PROTS + N_MOLS) * DIM / 8;   // 1,769,472
        convert_bf16<<<(unsigned)(groups / 256), 256, 0, stream>>>(prot, mol, protBf, molBf);
        dim3 grid(64, 8);
        sim_pass_bf16<<<grid, 512, 0, stream>>>(protBf, molBf, lscale, row_se, col_se, pos_sim, scalars);
    } else {
        dim3 grid(N_MOLS / 128, N_PROTS / 128);
        sim_pass<<<grid, 256, 0, stream>>>(prot, mol, lscale, row_se, col_se, pos_sim, scalars);
    }
    finalize1<<<N_MOLS / 256, 256, 0, stream>>>(row_se, col_se, pos_sim, pic50, scalars);
    finalize2<<<1, 1, 0, stream>>>(scalars, (float*)d_out);
}

// Round 5
// 425.669 us; speedup vs baseline: 1.6115x; 1.6115x over previous
//
#include <hip/hip_runtime.h>
#include <hip/hip_bf16.h>
#include <math.h>

#define N_PROTS 2048
#define N_MOLS  16384
#define DIM     768
#define SHIFT   16.0f
#define MARGIN  0.5f

typedef __attribute__((ext_vector_type(8))) short short8;
typedef __attribute__((ext_vector_type(4))) float f32x4;
typedef __attribute__((ext_vector_type(4))) unsigned short us4;
typedef __attribute__((ext_vector_type(8))) unsigned short us8;

__device__ __forceinline__ unsigned short bf16rnd(float x) {
    unsigned int u = __float_as_uint(x);
    u += 0x7fffu + ((u >> 16) & 1u);   // round-to-nearest-even
    return (unsigned short)(u >> 16);
}

__device__ __forceinline__ void gload16(const void* g, void* l) {
    __builtin_amdgcn_global_load_lds(
        (const __attribute__((address_space(1))) unsigned int*)g,
        (__attribute__((address_space(3))) unsigned int*)l, 16, 0, 0);
}

// ws layout:
//  floats [0, 34824): 0..2048 row_sumexp | 2048..18432 col_sumexp |
//                     18432..34816 pos_sim | 34816..34824 scalars
//  then 16B-aligned: protBf (2048*768 bf16, CHUNK-SWIZZLED), molBf (16384*768 bf16, linear)
#define ACC_FLOATS 34824
#define PROT_BF_OFF_B 139296ull                      // 34824*4, 16B aligned
#define PROT_BF_BYTES (2048ull*768*2)
#define MOL_BF_OFF_B  (PROT_BF_OFF_B + PROT_BF_BYTES)
#define MOL_BF_BYTES  (16384ull*768*2)
#define WS_NEED       (MOL_BF_OFF_B + MOL_BF_BYTES)  // ~28.5 MB

// ---------------- one-shot fp32 -> bf16 conversion ----------------
// prot rows are written with 16B-chunk swizzle c' = c ^ (row&7) so that the
// GEMM's verbatim slab copy into LDS gives conflict-free ds_read_b128
// (row stride 1536 B == 0 mod 128 B would otherwise alias all 16 lanes).
__global__ __launch_bounds__(256)
void convert_bf16(const float* __restrict__ prot, const float* __restrict__ mol,
                  unsigned short* __restrict__ protBf, unsigned short* __restrict__ molBf)
{
    const size_t PROT_G = (size_t)N_PROTS * DIM / 8;   // 16B chunks
    size_t t = (size_t)blockIdx.x * 256 + threadIdx.x;
    const float* src;
    unsigned short* dst;
    if (t < PROT_G) {
        int row = (int)(t / (DIM / 8));
        int c   = (int)(t - (size_t)row * (DIM / 8));
        src = prot + t * 8;
        dst = protBf + (size_t)row * DIM + ((c ^ (row & 7)) << 3);
    } else {
        size_t u = t - PROT_G;
        src = mol + u * 8;
        dst = molBf + u * 8;
    }
    float4 v0 = ((const float4*)src)[0];
    float4 v1 = ((const float4*)src)[1];
    us8 o;
    o[0] = bf16rnd(v0.x); o[1] = bf16rnd(v0.y); o[2] = bf16rnd(v0.z); o[3] = bf16rnd(v0.w);
    o[4] = bf16rnd(v1.x); o[5] = bf16rnd(v1.y); o[6] = bf16rnd(v1.z); o[7] = bf16rnd(v1.w);
    *(us8*)dst = o;
}

// ------- GEMM: A(64 rows x K) resident in LDS, B streamed to registers, ------
// ------- NO barrier in the K-loop (compiler pipelines B loads via vmcnt) -----
__global__ __launch_bounds__(512, 2)
void sim_pass_reg(const unsigned short* __restrict__ protBf,   // swizzled
                  const unsigned short* __restrict__ molBf,    // linear
                  const float* __restrict__ scale_p,
                  float* __restrict__ row_se, float* __restrict__ col_se,
                  float* __restrict__ pos_sim, float* __restrict__ scalars)
{
    __shared__ unsigned short Asl[64 * DIM];   // 96 KB
    __shared__ float redBuf[8];

    const int tid  = threadIdx.x;
    const int wave = tid >> 6;        // 0..7
    const int lane = tid & 63;
    const int l15  = lane & 15;
    const int q    = lane >> 4;       // 0..3

    // grid 1024 linear: bx = col group (512 cols), by = row group (64 rows).
    // XCD = l&7 sees bx in {x, x+8, x+16, x+24} -> 3 MB of B per XCD L2.
    const int l  = blockIdx.x;
    const int bx = l & 31;
    const int by = l >> 5;
    const int rowBase = by * 64;
    const int colBase = bx * 512 + wave * 64;

    // ---- stage A slab (contiguous 96 KB, already swizzled) ----
    {
        const unsigned short* aSlab = protBf + (size_t)rowBase * DIM;
#pragma unroll
        for (int i = 0; i < 12; ++i) {
            int c = tid + 512 * i;              // 16B chunk index, 0..6143
            gload16(aSlab + (size_t)c * 8, &Asl[(size_t)c * 8]);
        }
    }
    __syncthreads();   // single barrier; K-loop below is barrier-free

    f32x4 acc[4][4];
#pragma unroll
    for (int i = 0; i < 4; ++i)
#pragma unroll
        for (int j = 0; j < 4; ++j) acc[i][j] = (f32x4){0.f, 0.f, 0.f, 0.f};

    // B base pointers: lane (ni,l15) reads mol row colBase+ni*16+l15,
    // 16B at k-chunk (s*4+q)  -> immediate offset s*64+q*16 bytes.
    const unsigned short* bPtr[4];
#pragma unroll
    for (int ni = 0; ni < 4; ++ni)
        bPtr[ni] = molBf + (size_t)(colBase + ni * 16 + l15) * DIM + q * 8;

    const int swzh = l15 & 7;   // A-chunk swizzle key (row&7 == l15&7)

    short8 bA[4], bB[4], bC[4];
#pragma unroll
    for (int ni = 0; ni < 4; ++ni) bA[ni] = *(const short8*)(bPtr[ni]);        // s=0
#pragma unroll
    for (int ni = 0; ni < 4; ++ni) bB[ni] = *(const short8*)(bPtr[ni] + 32);   // s=1

#define LOADB(dst, ss)                                                          \
    {   int _s = ((ss) < DIM / 32) ? (ss) : 0;                                  \
        _Pragma("unroll")                                                       \
        for (int ni = 0; ni < 4; ++ni)                                          \
            dst[ni] = *(const short8*)(bPtr[ni] + _s * 32);                     \
    }

#define COMPUTE(ss, bReg)                                                       \
    {   const int _x = (((ss) * 4 + q) ^ swzh) << 3;                            \
        short8 aF[4];                                                           \
        _Pragma("unroll")                                                       \
        for (int mi = 0; mi < 4; ++mi)                                          \
            aF[mi] = *(const short8*)&Asl[(mi * 16 + l15) * DIM + _x];          \
        _Pragma("unroll")                                                       \
        for (int mi = 0; mi < 4; ++mi)                                          \
            _Pragma("unroll")                                                   \
            for (int ni = 0; ni < 4; ++ni)                                      \
                acc[mi][ni] = __builtin_amdgcn_mfma_f32_16x16x32_bf16(          \
                    aF[mi], bReg[ni], acc[mi][ni], 0, 0, 0);                    \
    }

#pragma unroll 1
    for (int s = 0; s < DIM / 32; s += 3) {
        LOADB(bC, s + 2);
        COMPUTE(s, bA);
        LOADB(bA, s + 3);
        COMPUTE(s + 1, bB);
        LOADB(bB, s + 4);
        COMPUTE(s + 2, bC);
    }
#undef LOADB
#undef COMPUTE

    // ---------------- epilogue ----------------
    const float scale = scale_p[0];
    float rsum[4][4];
    float csum[4] = {0.f, 0.f, 0.f, 0.f};
    float rl = 0.f;
#pragma unroll
    for (int mi = 0; mi < 4; ++mi)
#pragma unroll
        for (int r = 0; r < 4; ++r) rsum[mi][r] = 0.f;

#pragma unroll
    for (int mi = 0; mi < 4; ++mi) {
#pragma unroll
        for (int ni = 0; ni < 4; ++ni) {
#pragma unroll
            for (int r = 0; r < 4; ++r) {
                float sim = acc[mi][ni][r] * scale;
                float e = __expf(sim - SHIFT);
                rsum[mi][r] += e;
                csum[ni] += e;
                rl += fmaxf(sim, 0.f);
                int rg = rowBase + mi * 16 + q * 4 + r;
                int cg = colBase + ni * 16 + l15;
                if ((cg >> 3) == rg) pos_sim[cg] = sim;   // unique writer
            }
        }
    }

#pragma unroll
    for (int mi = 0; mi < 4; ++mi) {
#pragma unroll
        for (int r = 0; r < 4; ++r) {
            float v = rsum[mi][r];
            v += __shfl_xor(v, 1); v += __shfl_xor(v, 2);
            v += __shfl_xor(v, 4); v += __shfl_xor(v, 8);
            if (l15 == 0)
                atomicAdd(&row_se[rowBase + mi * 16 + q * 4 + r], v);
        }
    }
#pragma unroll
    for (int ni = 0; ni < 4; ++ni) {
        float v = csum[ni];
        v += __shfl_xor(v, 16); v += __shfl_xor(v, 32);
        if (q == 0)
            atomicAdd(&col_se[colBase + ni * 16 + l15], v);
    }
#pragma unroll
    for (int m = 1; m < 64; m <<= 1) rl += __shfl_xor(rl, m);
    if (lane == 0) redBuf[wave] = rl;
    __syncthreads();
    if (tid == 0) {
        float t = 0.f;
        for (int w = 0; w < 8; ++w) t += redBuf[w];
        atomicAdd(&scalars[0], t);
    }
}

// ---------------- fallback: fp32-staging GEMM (R1 kernel, known-good) --------
__global__ __launch_bounds__(256, 2)
void sim_pass(const float* __restrict__ prot, const float* __restrict__ mol,
              const float* __restrict__ scale_p,
              float* __restrict__ row_se, float* __restrict__ col_se,
              float* __restrict__ pos_sim, float* __restrict__ scalars)
{
    __shared__ unsigned short As[128][32];
    __shared__ unsigned short Bs[128][32];
    __shared__ float redBuf[4];

    const int tid = threadIdx.x;
    const int rowBase = blockIdx.y * 128;
    const int colBase = blockIdx.x * 128;
    const int wave = tid >> 6;
    const int lane = tid & 63;
    const int wr = (wave >> 1) * 64;
    const int wc = (wave & 1) * 64;
    const int l15 = lane & 15;
    const int q   = lane >> 4;

    f32x4 acc[4][4];
#pragma unroll
    for (int i = 0; i < 4; ++i)
#pragma unroll
        for (int j = 0; j < 4; ++j) acc[i][j] = (f32x4){0.f, 0.f, 0.f, 0.f};

    const float* aBase = prot + (size_t)rowBase * DIM;
    const float* bBase = mol  + (size_t)colBase * DIM;
    float4 aReg[4], bReg[4];
#pragma unroll
    for (int i = 0; i < 4; ++i) {
        int f = tid + 256 * i;
        int row = f >> 3, c4 = f & 7;
        aReg[i] = *(const float4*)(aBase + (size_t)row * DIM + (c4 << 2));
        bReg[i] = *(const float4*)(bBase + (size_t)row * DIM + (c4 << 2));
    }
#pragma unroll 1
    for (int s = 0; s < DIM / 32; ++s) {
#pragma unroll
        for (int i = 0; i < 4; ++i) {
            int f = tid + 256 * i;
            int row = f >> 3, c4 = f & 7;
            us4 av, bv;
            av.x = bf16rnd(aReg[i].x); av.y = bf16rnd(aReg[i].y);
            av.z = bf16rnd(aReg[i].z); av.w = bf16rnd(aReg[i].w);
            bv.x = bf16rnd(bReg[i].x); bv.y = bf16rnd(bReg[i].y);
            bv.z = bf16rnd(bReg[i].z); bv.w = bf16rnd(bReg[i].w);
            *(us4*)&As[row][c4 << 2] = av;
            *(us4*)&Bs[row][c4 << 2] = bv;
        }
        __syncthreads();
        if (s + 1 < DIM / 32) {
            int k0 = (s + 1) * 32;
#pragma unroll
            for (int i = 0; i < 4; ++i) {
                int f = tid + 256 * i;
                int row = f >> 3, c4 = f & 7;
                aReg[i] = *(const float4*)(aBase + (size_t)row * DIM + k0 + (c4 << 2));
                bReg[i] = *(const float4*)(bBase + (size_t)row * DIM + k0 + (c4 << 2));
            }
        }
        short8 aF[4], bF[4];
#pragma unroll
        for (int mi = 0; mi < 4; ++mi) aF[mi] = *(const short8*)&As[wr + mi * 16 + l15][q * 8];
#pragma unroll
        for (int ni = 0; ni < 4; ++ni) bF[ni] = *(const short8*)&Bs[wc + ni * 16 + l15][q * 8];
#pragma unroll
        for (int mi = 0; mi < 4; ++mi)
#pragma unroll
            for (int ni = 0; ni < 4; ++ni)
                acc[mi][ni] = __builtin_amdgcn_mfma_f32_16x16x32_bf16(aF[mi], bF[ni], acc[mi][ni], 0, 0, 0);
        __syncthreads();
    }

    const float scale = scale_p[0];
    float rsum[4][4];
    float csum[4] = {0.f, 0.f, 0.f, 0.f};
    float rl = 0.f;
#pragma unroll
    for (int mi = 0; mi < 4; ++mi)
#pragma unroll
        for (int r = 0; r < 4; ++r) rsum[mi][r] = 0.f;
#pragma unroll
    for (int mi = 0; mi < 4; ++mi) {
#pragma unroll
        for (int ni = 0; ni < 4; ++ni) {
#pragma unroll
            for (int r = 0; r < 4; ++r) {
                float sim = acc[mi][ni][r] * scale;
                float e = __expf(sim - SHIFT);
                rsum[mi][r] += e;
                csum[ni] += e;
                rl += fmaxf(sim, 0.f);
                int rg = rowBase + wr + mi * 16 + q * 4 + r;
                int cg = colBase + wc + ni * 16 + l15;
                if ((cg >> 3) == rg) pos_sim[cg] = sim;
            }
        }
    }
#pragma unroll
    for (int mi = 0; mi < 4; ++mi) {
#pragma unroll
        for (int r = 0; r < 4; ++r) {
            float v = rsum[mi][r];
            v += __shfl_xor(v, 1); v += __shfl_xor(v, 2);
            v += __shfl_xor(v, 4); v += __shfl_xor(v, 8);
            if (l15 == 0)
                atomicAdd(&row_se[rowBase + wr + mi * 16 + q * 4 + r], v);
        }
    }
#pragma unroll
    for (int ni = 0; ni < 4; ++ni) {
        float v = csum[ni];
        v += __shfl_xor(v, 16); v += __shfl_xor(v, 32);
        if (q == 0)
            atomicAdd(&col_se[colBase + wc + ni * 16 + l15], v);
    }
#pragma unroll
    for (int m = 1; m < 64; m <<= 1) rl += __shfl_xor(rl, m);
    if (lane == 0) redBuf[wave] = rl;
    __syncthreads();
    if (tid == 0)
        atomicAdd(&scalars[0], redBuf[0] + redBuf[1] + redBuf[2] + redBuf[3]);
}

// ---------------- finalize ----------------
__global__ __launch_bounds__(256)
void finalize1(const float* __restrict__ row_se, const float* __restrict__ col_se,
               const float* __restrict__ pos_sim, const float* __restrict__ pic50,
               float* __restrict__ scalars)
{
    int j = blockIdx.x * 256 + threadIdx.x;   // mol index
    float m2p = SHIFT + __logf(col_se[j]) - pos_sim[j];

    float p2m = 0.f, rank = 0.f, prelu = 0.f;
    if ((j & 7) == 0) {
        int i = j >> 3;
        float s[8], pc[8], pr[8];
#pragma unroll
        for (int p = 0; p < 8; ++p) {
            s[p]  = pos_sim[j + p];
            pr[p] = pic50[(size_t)i * N_MOLS + j + p];
            float x = (pr[p] - 2.0f) * 0.125f;
            pc[p] = fminf(fmaxf(x, 0.f), 1.f);
            prelu += fmaxf(s[p], 0.f);
        }
        float wsum = 1e-8f;
#pragma unroll
        for (int p = 0; p < 8; ++p) wsum += pc[p];
        float lse = SHIFT + __logf(row_se[i]);
        float accp = 0.f;
#pragma unroll
        for (int p = 0; p < 8; ++p) accp += pc[p] * (lse - s[p]);
        p2m = accp / wsum;
#pragma unroll
        for (int a = 0; a < 8; ++a)
#pragma unroll
            for (int b = a + 1; b < 8; ++b) {
                float dp = pr[a] - pr[b];
                float ds = s[a] - s[b];
                float v = (dp > 0.f) ? fmaxf(MARGIN - ds, 0.f)
                        : ((dp < 0.f) ? fmaxf(MARGIN + ds, 0.f) : 0.f);
                rank += v;
            }
    }

#pragma unroll
    for (int m = 1; m < 64; m <<= 1) {
        m2p   += __shfl_xor(m2p, m);
        p2m   += __shfl_xor(p2m, m);
        rank  += __shfl_xor(rank, m);
        prelu += __shfl_xor(prelu, m);
    }
    __shared__ float rbuf[4][4];
    int wave = threadIdx.x >> 6, lane = threadIdx.x & 63;
    if (lane == 0) { rbuf[wave][0] = m2p; rbuf[wave][1] = p2m; rbuf[wave][2] = rank; rbuf[wave][3] = prelu; }
    __syncthreads();
    if (threadIdx.x == 0) {
        float a = 0, b = 0, c = 0, d = 0;
        for (int w = 0; w < 4; ++w) { a += rbuf[w][0]; b += rbuf[w][1]; c += rbuf[w][2]; d += rbuf[w][3]; }
        atomicAdd(&scalars[2], a);
        atomicAdd(&scalars[1], b);
        atomicAdd(&scalars[3], c);
        atomicAdd(&scalars[4], d);
    }
}

__global__ void finalize2(const float* __restrict__ scalars, float* __restrict__ out)
{
    float relu_neg = scalars[0] - scalars[4];
    float p2m  = scalars[1] / (float)N_PROTS;
    float m2p  = scalars[2] / (float)N_MOLS;
    float rank = scalars[3] / ((float)N_PROTS * 28.0f);
    float neg  = relu_neg / ((float)N_PROTS * (float)N_MOLS);
    out[0] = p2m + m2p + 0.5f * rank + 0.1f * neg;
    out[1] = p2m;
    out[2] = m2p;
    out[3] = rank;
    out[4] = neg;
}

extern "C" void kernel_launch(void* const* d_in, const int* in_sizes, int n_in,
                              void* d_out, int out_size, void* d_ws, size_t ws_size,
                              hipStream_t stream) {
    const float* prot   = (const float*)d_in[0];
    const float* mol    = (const float*)d_in[1];
    const float* pic50  = (const float*)d_in[3];
    const float* lscale = (const float*)d_in[4];

    float* ws      = (float*)d_ws;
    float* row_se  = ws;
    float* col_se  = ws + 2048;
    float* pos_sim = ws + 2048 + 16384;
    float* scalars = ws + 2048 + 16384 + 16384;

    hipMemsetAsync(d_ws, 0, (size_t)ACC_FLOATS * sizeof(float), stream);

    if (ws_size >= WS_NEED) {
        unsigned short* protBf = (unsigned short*)((char*)d_ws + PROT_BF_OFF_B);
        unsigned short* molBf  = (unsigned short*)((char*)d_ws + MOL_BF_OFF_B);
        size_t groups = ((size_t)N_PROTS + N_MOLS) * DIM / 8;   // 1,769,472
        convert_bf16<<<(unsigned)(groups / 256), 256, 0, stream>>>(prot, mol, protBf, molBf);
        sim_pass_reg<<<1024, 512, 0, stream>>>(protBf, molBf, lscale, row_se, col_se, pos_sim, scalars);
    } else {
        dim3 grid(N_MOLS / 128, N_PROTS / 128);
        sim_pass<<<grid, 256, 0, stream>>>(prot, mol, lscale, row_se, col_se, pos_sim, scalars);
    }
    finalize1<<<N_MOLS / 256, 256, 0, stream>>>(row_se, col_se, pos_sim, pic50, scalars);
    finalize2<<<1, 1, 0, stream>>>(scalars, (float*)d_out);
}

// Round 6
// 382.894 us; speedup vs baseline: 1.7916x; 1.1117x over previous
//
#include <hip/hip_runtime.h>
#include <hip/hip_bf16.h>
#include <math.h>

#define N_PROTS 2048
#define N_MOLS  16384
#define DIM     768
#define SHIFT   16.0f
#define MARGIN  0.5f

typedef __attribute__((ext_vector_type(8))) short short8;
typedef __attribute__((ext_vector_type(4))) float f32x4;
typedef __attribute__((ext_vector_type(4))) unsigned short us4;
typedef __attribute__((ext_vector_type(8))) unsigned short us8;

__device__ __forceinline__ unsigned short bf16rnd(float x) {
    unsigned int u = __float_as_uint(x);
    u += 0x7fffu + ((u >> 16) & 1u);   // round-to-nearest-even
    return (unsigned short)(u >> 16);
}

__device__ __forceinline__ void gload16(const void* g, void* l) {
    __builtin_amdgcn_global_load_lds(
        (const __attribute__((address_space(1))) unsigned int*)g,
        (__attribute__((address_space(3))) unsigned int*)l, 16, 0, 0);
}

// ws layout:
//  floats [0, 34824): 0..2048 row_sumexp | 2048..18432 col_sumexp |
//                     18432..34816 pos_sim | 34816..34824 scalars
//  then 16B-aligned: protBf (2048*768 bf16, linear), molBf (16384*768 bf16, linear)
#define ACC_FLOATS 34824
#define PROT_BF_OFF_B 139296ull                      // 34824*4, 16B aligned
#define PROT_BF_BYTES (2048ull*768*2)
#define MOL_BF_OFF_B  (PROT_BF_OFF_B + PROT_BF_BYTES)
#define MOL_BF_BYTES  (16384ull*768*2)
#define WS_NEED       (MOL_BF_OFF_B + MOL_BF_BYTES)  // ~28.5 MB

// ---------------- one-shot fp32 -> bf16 conversion ----------------
__global__ __launch_bounds__(256)
void convert_bf16(const float* __restrict__ prot, const float* __restrict__ mol,
                  unsigned short* __restrict__ protBf, unsigned short* __restrict__ molBf)
{
    const size_t PROT_G = (size_t)N_PROTS * DIM / 8;   // 16B chunks
    size_t t = (size_t)blockIdx.x * 256 + threadIdx.x;
    const float* src;
    unsigned short* dst;
    if (t < PROT_G) { src = prot + t * 8; dst = protBf + t * 8; }
    else            { size_t u = t - PROT_G; src = mol + u * 8; dst = molBf + u * 8; }
    float4 v0 = ((const float4*)src)[0];
    float4 v1 = ((const float4*)src)[1];
    us8 o;
    o[0] = bf16rnd(v0.x); o[1] = bf16rnd(v0.y); o[2] = bf16rnd(v0.z); o[3] = bf16rnd(v0.w);
    o[4] = bf16rnd(v1.x); o[5] = bf16rnd(v1.y); o[6] = bf16rnd(v1.z); o[7] = bf16rnd(v1.w);
    *(us8*)dst = o;
}

// ------- bf16 GEMM: 128x128 tile, BK=64, single-buffer, global_load_lds ------
// 12 K-iterations (half of R2's 24) -> half the barrier-drain events.
// launch_bounds(256,3): unified-reg cap 170 (need ~140, no spill) -> 3 blocks/CU.
__global__ __launch_bounds__(256, 3)
void sim_pass_bf16(const unsigned short* __restrict__ protBf,
                   const unsigned short* __restrict__ molBf,
                   const float* __restrict__ scale_p,
                   float* __restrict__ row_se, float* __restrict__ col_se,
                   float* __restrict__ pos_sim, float* __restrict__ scalars)
{
    __shared__ unsigned short As[128][64];   // 16 KB
    __shared__ unsigned short Bs[128][64];   // 16 KB
    __shared__ float redBuf[4];

    const int tid = threadIdx.x;
    // XCD-aware remap: grid 2048 linear; xcd = l&7 owns a 16-wide bx band,
    // so each XCD's concurrent B slice = 16*128 = 2048 cols = 3 MB (fits L2).
    const int l    = blockIdx.x;
    const int xcd  = l & 7;
    const int slot = l >> 3;                 // 0..255
    const int bx   = xcd * 16 + (slot & 15); // 0..127
    const int by   = slot >> 4;              // 0..15
    const int rowBase = by * 128;
    const int colBase = bx * 128;

    const int wave = tid >> 6;
    const int lane = tid & 63;
    const int wr = (wave >> 1) * 64;
    const int wc = (wave & 1) * 64;
    const int l15 = lane & 15;
    const int q   = lane >> 4;

    f32x4 acc[4][4];
#pragma unroll
    for (int i = 0; i < 4; ++i)
#pragma unroll
        for (int j = 0; j < 4; ++j) acc[i][j] = (f32x4){0.f, 0.f, 0.f, 0.f};

    // Staging (BK=64: each row is 8 chunks of 16 B). Wave w, round i covers
    // rows w*32+i*8 .. +8. Lane: rsub = lane>>3 (row within 8), cs = lane&7
    // (LDS chunk slot). Source chunk is XOR-swizzled: c = cs ^ (r&7), with
    // r&7 == rsub, so LDS slot cs of row r holds global chunk cs^(r&7).
    // Fragment reads then use slot (k_chunk)^(r&7): rows r and r+8 alias ->
    // 2-way conflict = free.
    const int rsub = lane >> 3;                        // 0..7
    const int cs   = lane & 7;
    const int csrc = (cs ^ rsub) << 3;                 // halfword offset in row
    const unsigned short* aP =
        protBf + (size_t)(rowBase + wave * 32 + rsub) * DIM + csrc;
    const unsigned short* bP =
        molBf  + (size_t)(colBase + wave * 32 + rsub) * DIM + csrc;
    unsigned short* ldsA = &As[0][0] + (wave * 32) * 64;   // wave-uniform
    unsigned short* ldsB = &Bs[0][0] + (wave * 32) * 64;

#pragma unroll 1
    for (int s = 0; s < DIM / 64; ++s) {
        __syncthreads();   // all waves done reading previous stage
#pragma unroll
        for (int i = 0; i < 4; ++i) {
            gload16(aP + (size_t)i * 8 * DIM + s * 64, ldsA + i * 8 * 64);
            gload16(bP + (size_t)i * 8 * DIM + s * 64, ldsB + i * 8 * 64);
        }
        __syncthreads();   // drain vmcnt + publish stage s

#pragma unroll
        for (int kk = 0; kk < 2; ++kk) {
            short8 aF[4], bF[4];
#pragma unroll
            for (int mi = 0; mi < 4; ++mi) {
                const int R = wr + mi * 16 + l15;
                aF[mi] = *(const short8*)&As[R][((kk * 4 + q) ^ (l15 & 7)) << 3];
            }
#pragma unroll
            for (int ni = 0; ni < 4; ++ni) {
                const int R = wc + ni * 16 + l15;
                bF[ni] = *(const short8*)&Bs[R][((kk * 4 + q) ^ (l15 & 7)) << 3];
            }
#pragma unroll
            for (int mi = 0; mi < 4; ++mi)
#pragma unroll
                for (int ni = 0; ni < 4; ++ni)
                    acc[mi][ni] = __builtin_amdgcn_mfma_f32_16x16x32_bf16(
                        aF[mi], bF[ni], acc[mi][ni], 0, 0, 0);
        }
    }

    // ---------------- epilogue ----------------
    const float scale = scale_p[0];
    float rsum[4][4];
    float csum[4] = {0.f, 0.f, 0.f, 0.f};
    float rl = 0.f;
#pragma unroll
    for (int mi = 0; mi < 4; ++mi)
#pragma unroll
        for (int r = 0; r < 4; ++r) rsum[mi][r] = 0.f;

#pragma unroll
    for (int mi = 0; mi < 4; ++mi) {
#pragma unroll
        for (int ni = 0; ni < 4; ++ni) {
#pragma unroll
            for (int r = 0; r < 4; ++r) {
                float sim = acc[mi][ni][r] * scale;
                float e = __expf(sim - SHIFT);
                rsum[mi][r] += e;
                csum[ni] += e;
                rl += fmaxf(sim, 0.f);
                int rg = rowBase + wr + mi * 16 + q * 4 + r;
                int cg = colBase + wc + ni * 16 + l15;
                if ((cg >> 3) == rg) pos_sim[cg] = sim;   // unique writer
            }
        }
    }

#pragma unroll
    for (int mi = 0; mi < 4; ++mi) {
#pragma unroll
        for (int r = 0; r < 4; ++r) {
            float v = rsum[mi][r];
            v += __shfl_xor(v, 1); v += __shfl_xor(v, 2);
            v += __shfl_xor(v, 4); v += __shfl_xor(v, 8);
            if (l15 == 0)
                atomicAdd(&row_se[rowBase + wr + mi * 16 + q * 4 + r], v);
        }
    }
#pragma unroll
    for (int ni = 0; ni < 4; ++ni) {
        float v = csum[ni];
        v += __shfl_xor(v, 16); v += __shfl_xor(v, 32);
        if (q == 0)
            atomicAdd(&col_se[colBase + wc + ni * 16 + l15], v);
    }
#pragma unroll
    for (int m = 1; m < 64; m <<= 1) rl += __shfl_xor(rl, m);
    if (lane == 0) redBuf[wave] = rl;
    __syncthreads();
    if (tid == 0)
        atomicAdd(&scalars[0], redBuf[0] + redBuf[1] + redBuf[2] + redBuf[3]);
}

// ---------------- fallback: fp32-staging GEMM (R1 kernel, known-good) --------
__global__ __launch_bounds__(256, 2)
void sim_pass(const float* __restrict__ prot, const float* __restrict__ mol,
              const float* __restrict__ scale_p,
              float* __restrict__ row_se, float* __restrict__ col_se,
              float* __restrict__ pos_sim, float* __restrict__ scalars)
{
    __shared__ unsigned short As[128][32];
    __shared__ unsigned short Bs[128][32];
    __shared__ float redBuf[4];

    const int tid = threadIdx.x;
    const int rowBase = blockIdx.y * 128;
    const int colBase = blockIdx.x * 128;
    const int wave = tid >> 6;
    const int lane = tid & 63;
    const int wr = (wave >> 1) * 64;
    const int wc = (wave & 1) * 64;
    const int l15 = lane & 15;
    const int q   = lane >> 4;

    f32x4 acc[4][4];
#pragma unroll
    for (int i = 0; i < 4; ++i)
#pragma unroll
        for (int j = 0; j < 4; ++j) acc[i][j] = (f32x4){0.f, 0.f, 0.f, 0.f};

    const float* aBase = prot + (size_t)rowBase * DIM;
    const float* bBase = mol  + (size_t)colBase * DIM;
    float4 aReg[4], bReg[4];
#pragma unroll
    for (int i = 0; i < 4; ++i) {
        int f = tid + 256 * i;
        int row = f >> 3, c4 = f & 7;
        aReg[i] = *(const float4*)(aBase + (size_t)row * DIM + (c4 << 2));
        bReg[i] = *(const float4*)(bBase + (size_t)row * DIM + (c4 << 2));
    }
#pragma unroll 1
    for (int s = 0; s < DIM / 32; ++s) {
#pragma unroll
        for (int i = 0; i < 4; ++i) {
            int f = tid + 256 * i;
            int row = f >> 3, c4 = f & 7;
            us4 av, bv;
            av.x = bf16rnd(aReg[i].x); av.y = bf16rnd(aReg[i].y);
            av.z = bf16rnd(aReg[i].z); av.w = bf16rnd(aReg[i].w);
            bv.x = bf16rnd(bReg[i].x); bv.y = bf16rnd(bReg[i].y);
            bv.z = bf16rnd(bReg[i].z); bv.w = bf16rnd(bReg[i].w);
            *(us4*)&As[row][c4 << 2] = av;
            *(us4*)&Bs[row][c4 << 2] = bv;
        }
        __syncthreads();
        if (s + 1 < DIM / 32) {
            int k0 = (s + 1) * 32;
#pragma unroll
            for (int i = 0; i < 4; ++i) {
                int f = tid + 256 * i;
                int row = f >> 3, c4 = f & 7;
                aReg[i] = *(const float4*)(aBase + (size_t)row * DIM + k0 + (c4 << 2));
                bReg[i] = *(const float4*)(bBase + (size_t)row * DIM + k0 + (c4 << 2));
            }
        }
        short8 aF[4], bF[4];
#pragma unroll
        for (int mi = 0; mi < 4; ++mi) aF[mi] = *(const short8*)&As[wr + mi * 16 + l15][q * 8];
#pragma unroll
        for (int ni = 0; ni < 4; ++ni) bF[ni] = *(const short8*)&Bs[wc + ni * 16 + l15][q * 8];
#pragma unroll
        for (int mi = 0; mi < 4; ++mi)
#pragma unroll
            for (int ni = 0; ni < 4; ++ni)
                acc[mi][ni] = __builtin_amdgcn_mfma_f32_16x16x32_bf16(aF[mi], bF[ni], acc[mi][ni], 0, 0, 0);
        __syncthreads();
    }

    const float scale = scale_p[0];
    float rsum[4][4];
    float csum[4] = {0.f, 0.f, 0.f, 0.f};
    float rl = 0.f;
#pragma unroll
    for (int mi = 0; mi < 4; ++mi)
#pragma unroll
        for (int r = 0; r < 4; ++r) rsum[mi][r] = 0.f;
#pragma unroll
    for (int mi = 0; mi < 4; ++mi) {
#pragma unroll
        for (int ni = 0; ni < 4; ++ni) {
#pragma unroll
            for (int r = 0; r < 4; ++r) {
                float sim = acc[mi][ni][r] * scale;
                float e = __expf(sim - SHIFT);
                rsum[mi][r] += e;
                csum[ni] += e;
                rl += fmaxf(sim, 0.f);
                int rg = rowBase + wr + mi * 16 + q * 4 + r;
                int cg = colBase + wc + ni * 16 + l15;
                if ((cg >> 3) == rg) pos_sim[cg] = sim;
            }
        }
    }
#pragma unroll
    for (int mi = 0; mi < 4; ++mi) {
#pragma unroll
        for (int r = 0; r < 4; ++r) {
            float v = rsum[mi][r];
            v += __shfl_xor(v, 1); v += __shfl_xor(v, 2);
            v += __shfl_xor(v, 4); v += __shfl_xor(v, 8);
            if (l15 == 0)
                atomicAdd(&row_se[rowBase + wr + mi * 16 + q * 4 + r], v);
        }
    }
#pragma unroll
    for (int ni = 0; ni < 4; ++ni) {
        float v = csum[ni];
        v += __shfl_xor(v, 16); v += __shfl_xor(v, 32);
        if (q == 0)
            atomicAdd(&col_se[colBase + wc + ni * 16 + l15], v);
    }
#pragma unroll
    for (int m = 1; m < 64; m <<= 1) rl += __shfl_xor(rl, m);
    if (lane == 0) redBuf[wave] = rl;
    __syncthreads();
    if (tid == 0)
        atomicAdd(&scalars[0], redBuf[0] + redBuf[1] + redBuf[2] + redBuf[3]);
}

// ---------------- finalize ----------------
__global__ __launch_bounds__(256)
void finalize1(const float* __restrict__ row_se, const float* __restrict__ col_se,
               const float* __restrict__ pos_sim, const float* __restrict__ pic50,
               float* __restrict__ scalars)
{
    int j = blockIdx.x * 256 + threadIdx.x;   // mol index
    float m2p = SHIFT + __logf(col_se[j]) - pos_sim[j];

    float p2m = 0.f, rank = 0.f, prelu = 0.f;
    if ((j & 7) == 0) {
        int i = j >> 3;
        float s[8], pc[8], pr[8];
#pragma unroll
        for (int p = 0; p < 8; ++p) {
            s[p]  = pos_sim[j + p];
            pr[p] = pic50[(size_t)i * N_MOLS + j + p];
            float x = (pr[p] - 2.0f) * 0.125f;
            pc[p] = fminf(fmaxf(x, 0.f), 1.f);
            prelu += fmaxf(s[p], 0.f);
        }
        float wsum = 1e-8f;
#pragma unroll
        for (int p = 0; p < 8; ++p) wsum += pc[p];
        float lse = SHIFT + __logf(row_se[i]);
        float accp = 0.f;
#pragma unroll
        for (int p = 0; p < 8; ++p) accp += pc[p] * (lse - s[p]);
        p2m = accp / wsum;
#pragma unroll
        for (int a = 0; a < 8; ++a)
#pragma unroll
            for (int b = a + 1; b < 8; ++b) {
                float dp = pr[a] - pr[b];
                float ds = s[a] - s[b];
                float v = (dp > 0.f) ? fmaxf(MARGIN - ds, 0.f)
                        : ((dp < 0.f) ? fmaxf(MARGIN + ds, 0.f) : 0.f);
                rank += v;
            }
    }

#pragma unroll
    for (int m = 1; m < 64; m <<= 1) {
        m2p   += __shfl_xor(m2p, m);
        p2m   += __shfl_xor(p2m, m);
        rank  += __shfl_xor(rank, m);
        prelu += __shfl_xor(prelu, m);
    }
    __shared__ float rbuf[4][4];
    int wave = threadIdx.x >> 6, lane = threadIdx.x & 63;
    if (lane == 0) { rbuf[wave][0] = m2p; rbuf[wave][1] = p2m; rbuf[wave][2] = rank; rbuf[wave][3] = prelu; }
    __syncthreads();
    if (threadIdx.x == 0) {
        float a = 0, b = 0, c = 0, d = 0;
        for (int w = 0; w < 4; ++w) { a += rbuf[w][0]; b += rbuf[w][1]; c += rbuf[w][2]; d += rbuf[w][3]; }
        atomicAdd(&scalars[2], a);
        atomicAdd(&scalars[1], b);
        atomicAdd(&scalars[3], c);
        atomicAdd(&scalars[4], d);
    }
}

__global__ void finalize2(const float* __restrict__ scalars, float* __restrict__ out)
{
    float relu_neg = scalars[0] - scalars[4];
    float p2m  = scalars[1] / (float)N_PROTS;
    float m2p  = scalars[2] / (float)N_MOLS;
    float rank = scalars[3] / ((float)N_PROTS * 28.0f);
    float neg  = relu_neg / ((float)N_PROTS * (float)N_MOLS);
    out[0] = p2m + m2p + 0.5f * rank + 0.1f * neg;
    out[1] = p2m;
    out[2] = m2p;
    out[3] = rank;
    out[4] = neg;
}

extern "C" void kernel_launch(void* const* d_in, const int* in_sizes, int n_in,
                              void* d_out, int out_size, void* d_ws, size_t ws_size,
                              hipStream_t stream) {
    const float* prot   = (const float*)d_in[0];
    const float* mol    = (const float*)d_in[1];
    const float* pic50  = (const float*)d_in[3];
    const float* lscale = (const float*)d_in[4];

    float* ws      = (float*)d_ws;
    float* row_se  = ws;
    float* col_se  = ws + 2048;
    float* pos_sim = ws + 2048 + 16384;
    float* scalars = ws + 2048 + 16384 + 16384;

    hipMemsetAsync(d_ws, 0, (size_t)ACC_FLOATS * sizeof(float), stream);

    if (ws_size >= WS_NEED) {
        unsigned short* protBf = (unsigned short*)((char*)d_ws + PROT_BF_OFF_B);
        unsigned short* molBf  = (unsigned short*)((char*)d_ws + MOL_BF_OFF_B);
        size_t groups = ((size_t)N_PROTS + N_MOLS) * DIM / 8;   // 1,769,472
        convert_bf16<<<(unsigned)(groups / 256), 256, 0, stream>>>(prot, mol, protBf, molBf);
        sim_pass_bf16<<<2048, 256, 0, stream>>>(protBf, molBf, lscale, row_se, col_se, pos_sim, scalars);
    } else {
        dim3 grid(N_MOLS / 128, N_PROTS / 128);
        sim_pass<<<grid, 256, 0, stream>>>(prot, mol, lscale, row_se, col_se, pos_sim, scalars);
    }
    finalize1<<<N_MOLS / 256, 256, 0, stream>>>(row_se, col_se, pos_sim, pic50, scalars);
    finalize2<<<1, 1, 0, stream>>>(scalars, (float*)d_out);
}